// Round 11
// baseline (180.587 us; speedup 1.0000x reference)
//
#include <hip/hip_runtime.h>
#include <hip/hip_bf16.h>

#define BATCH 64
#define CCH 128
#define SEQ 1024
#define NG 32
#define EPSV 1e-6f
#define SCALEV 0.044194173824159216f
// Q pre-scale: SCALE * log2(e), folded into Q at creation so attn uses exp2
#define QPRE (0.044194173824159216f * 1.4426950408889634f)

typedef short v8s __attribute__((ext_vector_type(8)));
typedef short v4s __attribute__((ext_vector_type(4)));
typedef float v4f __attribute__((ext_vector_type(4)));
typedef int   v4i __attribute__((ext_vector_type(4)));
typedef unsigned short us;

__device__ __forceinline__ us f2bf(float f) {
    __hip_bfloat16 h = __float2bfloat16(f);
    return *reinterpret_cast<us*>(&h);
}

// packed f32x2 -> bf16x2 (RNE), single VALU op
__device__ __forceinline__ int cvtpk(float lo, float hi) {
    int r;
    asm("v_cvt_pk_bf16_f32 %0, %1, %2" : "=v"(r) : "v"(lo), "v"(hi));
    return r;
}

#if __has_builtin(__builtin_amdgcn_exp2f)
#define EXP2F(x) __builtin_amdgcn_exp2f(x)
#else
#define EXP2F(x) exp2f(x)
#endif

#define MFMA16(a, b, c) __builtin_amdgcn_mfma_f32_16x16x32_bf16(a, b, c, 0, 0, 0)

// async global->LDS, 16B per lane; LDS dst = base + lane*16 (wave-uniform base)
__device__ __forceinline__ void gld_lds16(const us* g, us* l) {
    __builtin_amdgcn_global_load_lds(
        (const __attribute__((address_space(1))) void*)g,
        (__attribute__((address_space(3))) void*)l, 16, 0, 0);
}

// ---------------- fused: weights fp32->bf16 (blocks 0..255) + GN stats ------
__global__ void prep_gn(const float* __restrict__ wq, const float* __restrict__ wk,
                        const float* __restrict__ wv, const float* __restrict__ wo,
                        us* wbf, const float* __restrict__ x,
                        float* meanr, float* rstdr) {
    int tid = threadIdx.x;
    if (blockIdx.x < 256) {
        int i = blockIdx.x * 256 + tid;          // 0..65535
        const float* srcs[4] = {wq, wk, wv, wo};
        wbf[i] = f2bf(srcs[i >> 14][i & 16383]);
        return;
    }
    int bg = blockIdx.x - 256;                   // b*NG + g, 0..2047
    const float4* p = (const float4*)(x + (size_t)bg * (4 * SEQ));
    float s1 = 0.f, s2 = 0.f;
    #pragma unroll
    for (int i = 0; i < 4; i++) {
        float4 v = p[i * 256 + tid];
        s1 += v.x + v.y + v.z + v.w;
        s2 += v.x * v.x + v.y * v.y + v.z * v.z + v.w * v.w;
    }
    #pragma unroll
    for (int off = 32; off; off >>= 1) {
        s1 += __shfl_down(s1, off);
        s2 += __shfl_down(s2, off);
    }
    __shared__ float a1[4], a2[4];
    int w = tid >> 6, l = tid & 63;
    if (l == 0) { a1[w] = s1; a2[w] = s2; }
    __syncthreads();
    if (tid == 0) {
        float t1 = a1[0] + a1[1] + a1[2] + a1[3];
        float t2 = a2[0] + a2[1] + a2[2] + a2[3];
        float mean = t1 * (1.0f / (4 * SEQ));
        float var  = t2 * (1.0f / (4 * SEQ)) - mean * mean;
        meanr[bg] = mean;
        rstdr[bg] = rsqrtf(var + EPSV);
    }
}

// ---------------- fused GroupNorm-apply + QKV projection (R12, kept) --------
__global__ __launch_bounds__(256, 4) void qkv_kernel(
    const float* __restrict__ x, const float* __restrict__ gn_w,
    const float* __restrict__ gn_b, const float* __restrict__ meanr,
    const float* __restrict__ rstdr, const us* __restrict__ wbf,
    const float* __restrict__ bq, const float* __restrict__ bk,
    const float* __restrict__ bv,
    us* Q, us* K, us* Vt)
{
    __shared__ us tls[9216];                     // x-tile (pitch 136) / repack
    __shared__ float sa[CCH], sb[CCH];
    int b  = blockIdx.x >> 4;
    int s0 = (blockIdx.x & 15) * 64;
    int tid = threadIdx.x;
    const float* xb = x + (size_t)b * CCH * SEQ;

    if (tid < CCH) {
        int g = tid >> 2;
        float rs = rstdr[b * NG + g];
        float mu = meanr[b * NG + g];
        float a_ = rs * gn_w[tid];
        sa[tid] = a_;
        sb[tid] = gn_b[tid] - mu * a_;
    }
    __syncthreads();

    #pragma unroll
    for (int rep = 0; rep < 8; rep++) {
        int idx = rep * 256 + tid;               // 0..2047
        int c = idx >> 4, s4 = idx & 15;         // 4 seq elems per thread
        float4 v = *(const float4*)&xb[c * SEQ + s0 + s4 * 4];
        float a_ = sa[c], b_ = sb[c];
        int sbase = s4 * 4;
        tls[(sbase + 0) * 136 + c] = f2bf(v.x * a_ + b_);
        tls[(sbase + 1) * 136 + c] = f2bf(v.y * a_ + b_);
        tls[(sbase + 2) * 136 + c] = f2bf(v.z * a_ + b_);
        tls[(sbase + 3) * 136 + c] = f2bf(v.w * a_ + b_);
    }
    __syncthreads();

    int w = tid >> 6, lane = tid & 63;
    int m = lane & 15, quad = lane >> 4;

    // preload all x-tile A-frags (4 st x 4 ch = 64 VGPR); tls dead after
    v8s a[4][4];
    #pragma unroll
    for (int st = 0; st < 4; st++)
        #pragma unroll
        for (int ch = 0; ch < 4; ch++)
            a[st][ch] = *(const v8s*)&tls[(st * 16 + m) * 136 + ch * 32 + quad * 8];
    __syncthreads();                             // all waves preloaded

    us* Qb = Q + (size_t)b * SEQ * CCH;
    us* Kb = K + (size_t)b * SEQ * CCH;
    us* Vb = Vt + (size_t)b * CCH * SEQ;

    #pragma unroll
    for (int o = 0; o < 3; o++) {
        const us* wmat = wbf + o * 16384;
        const float* bb = (o == 0) ? bq : (o == 1) ? bk : bv;
        #pragma unroll
        for (int t2 = 0; t2 < 2; t2++) {
            int T = (o * 2 + t2) * 4 + w;        // wave-major over col-tiles
            int ct = T & 7;
            int col = ct * 16 + m;
            v8s bfr[4];
            #pragma unroll
            for (int ch = 0; ch < 4; ch++)
                bfr[ch] = *(const v8s*)&wmat[(ct * 16 + m) * 128 + ch * 32 + quad * 8];
            float bias = bb[col];
            #pragma unroll
            for (int st = 0; st < 4; st++) {
                v4f acc = {0,0,0,0};
                #pragma unroll
                for (int ch = 0; ch < 4; ch++)
                    acc = MFMA16(a[st][ch], bfr[ch], acc);
                if (o < 2) {
                    #pragma unroll
                    for (int r = 0; r < 4; r++) {
                        float v = acc[r] + bias;
                        if (o == 0) v *= QPRE;
                        tls[(st * 16 + quad * 4 + r) * 136 + col] = f2bf(v);
                    }
                } else {
                    #pragma unroll
                    for (int r = 0; r < 4; r++)
                        tls[col * 72 + st * 16 + quad * 4 + r] = f2bf(acc[r] + bias);
                }
            }
        }
        __syncthreads();                         // repack tile complete
        if (o < 2) {
            us* dst = (o == 0) ? Qb : Kb;
            #pragma unroll
            for (int rep = 0; rep < 4; rep++) {
                int idx = rep * 256 + tid;       // 0..1023
                int row = idx >> 4, c8 = idx & 15;
                *(v8s*)&dst[(size_t)(s0 + row) * 128 + c8 * 8] =
                    *(const v8s*)&tls[row * 136 + c8 * 8];
            }
        } else {
            #pragma unroll
            for (int rep = 0; rep < 4; rep++) {
                int idx = rep * 256 + tid;       // 0..1023
                int c = idx >> 3, c8 = idx & 7;
                *(v8s*)&Vb[(size_t)c * SEQ + s0 + c8 * 8] =
                    *(const v8s*)&tls[c * 72 + c8 * 8];
            }
        }
        if (o < 2) __syncthreads();              // before next matrix reuses tls
    }
}

// ---- flash attention + fused out-projection ---------------------------------
// R16: key-split WAVES (not blocks). 4 waves = 2 q-groups (64 q-rows, 4
// stripes) x 2 key-halves (32 keys). Each wave reads only its 32-key half
// of K and the matching k-slice of V: per-CU ds-read traffic -57% vs R11
// (the hidden saturated pipe). Staging/dbuf/vmcnt(8)/barriers identical to
// R11. Plain-exp softmax => additive merge across key-half pairs via one
// LDS f32 exchange after the loop.
__global__ __launch_bounds__(256, 2) void attn_kernel(
    const us* __restrict__ Q, const us* __restrict__ K,
    const us* __restrict__ Vt, const us* __restrict__ wbo,
    const float* __restrict__ bo, const float* __restrict__ x,
    float* __restrict__ out)
{
    __shared__ char smem_raw[65536];

    int i = blockIdx.x;
    int b  = (i & 7) * 8 + ((i >> 3) & 7);       // 8 batches per XCD
    int qt = i >> 6;                             // 0..7 (128-row q-tiles)
    int tid = threadIdx.x;
    int w = tid >> 6, lane = tid & 63;           // w in 0..3
    int qs = w & 1, kh = w >> 1;                 // q-group, key-half
    int m = lane & 15, quad = lane >> 4;
    int qrow0 = qt * 128 + qs * 64;
    const us* Qb = Q + (size_t)b * SEQ * CCH;
    const us* Kb = K + (size_t)b * SEQ * CCH;
    const us* Vb = Vt + (size_t)b * CCH * SEQ;

    // Q as B-frags of Q^T (four 16-row stripes per wave = 64 q-rows)
    v8s aq[4][4];
    #pragma unroll
    for (int st = 0; st < 4; st++)
        #pragma unroll
        for (int ch = 0; ch < 4; ch++)
            aq[st][ch] = *(const v8s*)&Qb[(size_t)(qrow0 + st * 16 + m) * 128 + ch * 32 + quad * 8];

    v4f oacc[4][8];
    #pragma unroll
    for (int st = 0; st < 4; st++)
        #pragma unroll
        for (int ct = 0; ct < 8; ct++) oacc[st][ct] = (v4f){0, 0, 0, 0};
    float lrun[4] = {0.f, 0.f, 0.f, 0.f};        // per-stripe partial rowsum

    // staging (identical to R11): wave w stages insts j = w*4 + j4
    const us* kg[4]; const us* vg[4];
    int jb = w * 4;
    #pragma unroll
    for (int j4 = 0; j4 < 4; j4++) {
        int j = jb + j4;
        int kr = 4 * j + (lane >> 4);
        kg[j4] = Kb + (size_t)kr * 128 + ((lane & 15) ^ (kr & 15)) * 8;
        int vc = 8 * j + (lane >> 3);
        vg[j4] = Vb + (size_t)vc * SEQ + ((lane & 7) ^ (vc & 7)) * 8;
    }
    int idx0 = 2 * (quad & 1) * 16 + m;          // bpermute source lanes
    int idx1 = idx0 + 16;

    // prologue: stage tile 0 into buf0 (K at +0, V at +16384)
    #pragma unroll
    for (int j4 = 0; j4 < 4; j4++) {
        gld_lds16(kg[j4], (us*)smem_raw + (jb + j4) * 512);
        gld_lds16(vg[j4], (us*)(smem_raw + 16384) + (jb + j4) * 512);
    }

    for (int kt = 0; kt < 16; kt++) {
        int boff  = (kt & 1) ? 32768 : 0;        // current buffer byte offset
        int boffn = boff ^ 32768;                // next buffer
        __builtin_amdgcn_s_barrier();            // all waves done with next buf
        if (kt < 15) {
            #pragma unroll
            for (int j4 = 0; j4 < 4; j4++) {
                gld_lds16(kg[j4] + (size_t)(kt + 1) * 8192,
                          (us*)(smem_raw + boffn) + (jb + j4) * 512);
                gld_lds16(vg[j4] + (size_t)(kt + 1) * 64,
                          (us*)(smem_raw + boffn + 16384) + (jb + j4) * 512);
            }
            asm volatile("s_waitcnt vmcnt(8)" ::: "memory");   // own tile-kt loads landed
        } else {
            asm volatile("s_waitcnt vmcnt(0)" ::: "memory");
        }
        __builtin_amdgcn_s_barrier();            // tile kt fully in LDS (all waves)

        const us* kl = (const us*)(smem_raw + boff);
        const us* vl = (const us*)(smem_raw + boff + 16384);

        __builtin_amdgcn_s_setprio(1);           // whole compute phase hi-prio

        int e[4][2][2];                          // [stripe][c2][pair]

        // ---- QK over this wave's 32-key half: 2 key-16-tiles x 4 stripes --
        #pragma unroll
        for (int c2 = 0; c2 < 2; c2++) {
            int krow = kh * 32 + c2 * 16 + m;    // lane m = key-within-16tile
            v4f A0 = {0,0,0,0}, A1 = {0,0,0,0}, A2 = {0,0,0,0}, A3 = {0,0,0,0};
            #pragma unroll
            for (int ch = 0; ch < 4; ch++) {
                int chunk = (ch * 4 + quad) ^ m; // krow & 15 == m
                v8s kb = *(const v8s*)&kl[krow * 128 + chunk * 8];
                A0 = MFMA16(kb, aq[0][ch], A0);
                A1 = MFMA16(kb, aq[1][ch], A1);
                A2 = MFMA16(kb, aq[2][ch], A2);
                A3 = MFMA16(kb, aq[3][ch], A3);
            }
            // exp2 + pack (Q pre-scaled)
            float p[4][4];
            #pragma unroll
            for (int r = 0; r < 4; r++) {
                p[0][r] = EXP2F(A0[r]);
                p[1][r] = EXP2F(A1[r]);
                p[2][r] = EXP2F(A2[r]);
                p[3][r] = EXP2F(A3[r]);
            }
            #pragma unroll
            for (int st = 0; st < 4; st++) {
                lrun[st] += p[st][0] + p[st][1] + p[st][2] + p[st][3];
                e[st][c2][0] = cvtpk(p[st][0], p[st][1]);
                e[st][c2][1] = cvtpk(p[st][2], p[st][3]);
            }
        }

        // ---- P -> A-frag transpose (bpermute), one 32-key chunk ----
        v8s pa[4];
        #pragma unroll
        for (int st = 0; st < 4; st++) {
            int c0 = (quad < 2) ? e[st][0][0] : e[st][1][0];
            int c1 = (quad < 2) ? e[st][0][1] : e[st][1][1];
            v4i t;
            t[0] = __shfl(c0, idx0);
            t[1] = __shfl(c1, idx0);
            t[2] = __shfl(c0, idx1);
            t[3] = __shfl(c1, idx1);
            pa[st] = __builtin_bit_cast(v8s, t);
        }
        // ---- PV over this wave's k-slice: 8 out-col tiles x 4 stripes ----
        #pragma unroll
        for (int ct = 0; ct < 8; ct++) {
            int vrow = ct * 16 + m;
            int chunk = (kh * 4 + quad) ^ (vrow & 7);
            v8s vb = *(const v8s*)&vl[vrow * 64 + chunk * 8];
            oacc[0][ct] = MFMA16(pa[0], vb, oacc[0][ct]);
            oacc[1][ct] = MFMA16(pa[1], vb, oacc[1][ct]);
            oacc[2][ct] = MFMA16(pa[2], vb, oacc[2][ct]);
            oacc[3][ct] = MFMA16(pa[3], vb, oacc[3][ct]);
        }
        __builtin_amdgcn_s_setprio(0);
    }

    // ---- merge epilogue: rowsums + O across key-half pairs ----
    float rs[4];
    #pragma unroll
    for (int st = 0; st < 4; st++) {
        float r_ = lrun[st];
        r_ += __shfl_xor(r_, 16);
        r_ += __shfl_xor(r_, 32);                // rowsum over wave's 32 keys
        rs[st] = r_;
    }
    __syncthreads();                             // main-loop LDS dead
    float* lf = (float*)smem_raw;                // l[2][128]
    if (quad == 0) {
        #pragma unroll
        for (int st = 0; st < 4; st++)
            lf[kh * 128 + qs * 64 + st * 16 + m] = rs[st];
    }
    __syncthreads();
    float inv_[4][4];
    #pragma unroll
    for (int st = 0; st < 4; st++) {
        v4f la = *(const v4f*)&lf[qs * 64 + st * 16 + quad * 4];
        v4f lb = *(const v4f*)&lf[128 + qs * 64 + st * 16 + quad * 4];
        #pragma unroll
        for (int r = 0; r < 4; r++) inv_[st][r] = 1.0f / (la[r] + lb[r]);
    }
    __syncthreads();                             // l area dead
    float* Oa = (float*)smem_raw;                // [128][128] f32, col-XOR swz
    if (kh == 0) {
        #pragma unroll
        for (int st = 0; st < 4; st++)
            #pragma unroll
            for (int ct = 0; ct < 8; ct++)
                #pragma unroll
                for (int r = 0; r < 4; r++)
                    Oa[(qs * 64 + st * 16 + quad * 4 + r) * 128 +
                       ((ct * 16 + m) ^ ((quad & 1) << 4))] = oacc[st][ct][r];
    }
    __syncthreads();
    if (kh == 1) {
        #pragma unroll
        for (int st = 0; st < 4; st++)
            #pragma unroll
            for (int ct = 0; ct < 8; ct++)
                #pragma unroll
                for (int r = 0; r < 4; r++) {
                    float v = oacc[st][ct][r] +
                        Oa[(qs * 64 + st * 16 + quad * 4 + r) * 128 +
                           ((ct * 16 + m) ^ ((quad & 1) << 4))];
                    oacc[st][ct][r] = v * inv_[st][r];
                }
    }
    __syncthreads();                             // Oa consumed
    us* olds = (us*)smem_raw;                    // [128][136] bf16
    if (kh == 1) {
        #pragma unroll
        for (int st = 0; st < 4; st++)
            #pragma unroll
            for (int ct = 0; ct < 8; ct++)
                #pragma unroll
                for (int r = 0; r < 4; r++)
                    olds[(qs * 64 + st * 16 + quad * 4 + r) * 136 + ct * 16 + m] =
                        f2bf(oacc[st][ct][r]);
    }
    __syncthreads();

    // ---- projection: out^T[c][s] = wo @ O^T, + bias + residual ----
    const float* xb = x + (size_t)b * CCH * SEQ;
    float* ob = out + (size_t)b * CCH * SEQ;
    int sbase = qt * 128 + w * 32;
    v8s obf[2][4];
    #pragma unroll
    for (int st = 0; st < 2; st++)
        #pragma unroll
        for (int ch = 0; ch < 4; ch++)
            obf[st][ch] = *(const v8s*)&olds[(w * 32 + st * 16 + m) * 136 + ch * 32 + quad * 8];
    #pragma unroll
    for (int mt = 0; mt < 8; mt++) {
        v8s af[4];
        #pragma unroll
        for (int ch = 0; ch < 4; ch++)
            af[ch] = *(const v8s*)&wbo[(mt * 16 + m) * 128 + ch * 32 + quad * 8];
        #pragma unroll
        for (int st = 0; st < 2; st++) {
            v4f acc = {0,0,0,0};
            #pragma unroll
            for (int ch = 0; ch < 4; ch++)
                acc = MFMA16(af[ch], obf[st][ch], acc);
            #pragma unroll
            for (int r = 0; r < 4; r++) {
                int c = mt * 16 + quad * 4 + r;
                int idx = c * SEQ + sbase + st * 16 + m;
                ob[idx] = acc[r] + bo[c] + xb[idx];
            }
        }
    }
}

extern "C" void kernel_launch(void* const* d_in, const int* in_sizes, int n_in,
                              void* d_out, int out_size, void* d_ws, size_t ws_size,
                              hipStream_t stream) {
    const float* x    = (const float*)d_in[0];
    const float* gn_w = (const float*)d_in[1];
    const float* gn_b = (const float*)d_in[2];
    const float* wq   = (const float*)d_in[3];
    const float* bq   = (const float*)d_in[4];
    const float* wk   = (const float*)d_in[5];
    const float* bk   = (const float*)d_in[6];
    const float* wv   = (const float*)d_in[7];
    const float* bv   = (const float*)d_in[8];
    const float* wo   = (const float*)d_in[9];
    const float* bo   = (const float*)d_in[10];
    float* out = (float*)d_out;

    char* ws = (char*)d_ws;
    us* wbf      = (us*)ws;
    float* meanr = (float*)(ws + 131072);
    float* rstdr = (float*)(ws + 139264);
    us* Qbuf     = (us*)(ws + 147456);
    us* Kbuf     = (us*)(ws + 147456 + 16777216ull);
    us* Vtbuf    = (us*)(ws + 147456 + 2ull * 16777216ull);

    prep_gn<<<256 + BATCH * NG, 256, 0, stream>>>(wq, wk, wv, wo, wbf, x, meanr, rstdr);
    qkv_kernel<<<1024, 256, 0, stream>>>(x, gn_w, gn_b, meanr, rstdr, wbf,
                                         bq, bk, bv, Qbuf, Kbuf, Vtbuf);
    attn_kernel<<<512, 256, 0, stream>>>(Qbuf, Kbuf, Vtbuf, wbf + 3 * 16384,
                                         bo, x, out);
}

// Round 12
// 164.985 us; speedup vs baseline: 1.0946x; 1.0946x over previous
//
#include <hip/hip_runtime.h>
#include <hip/hip_bf16.h>

#define BATCH 64
#define CCH 128
#define SEQ 1024
#define NG 32
#define EPSV 1e-6f
#define SCALEV 0.044194173824159216f
// Q pre-scale: SCALE * log2(e), folded into Q at creation so attn uses exp2
#define QPRE (0.044194173824159216f * 1.4426950408889634f)

typedef short v8s __attribute__((ext_vector_type(8)));
typedef short v4s __attribute__((ext_vector_type(4)));
typedef float v4f __attribute__((ext_vector_type(4)));
typedef int   v4i __attribute__((ext_vector_type(4)));
typedef unsigned short us;

__device__ __forceinline__ us f2bf(float f) {
    __hip_bfloat16 h = __float2bfloat16(f);
    return *reinterpret_cast<us*>(&h);
}

// packed f32x2 -> bf16x2 (RNE), single VALU op
__device__ __forceinline__ int cvtpk(float lo, float hi) {
    int r;
    asm("v_cvt_pk_bf16_f32 %0, %1, %2" : "=v"(r) : "v"(lo), "v"(hi));
    return r;
}

#if __has_builtin(__builtin_amdgcn_exp2f)
#define EXP2F(x) __builtin_amdgcn_exp2f(x)
#else
#define EXP2F(x) exp2f(x)
#endif

#define MFMA16(a, b, c) __builtin_amdgcn_mfma_f32_16x16x32_bf16(a, b, c, 0, 0, 0)

// async global->LDS, 16B per lane; LDS dst = base + lane*16 (wave-uniform base)
__device__ __forceinline__ void gld_lds16(const us* g, us* l) {
    __builtin_amdgcn_global_load_lds(
        (const __attribute__((address_space(1))) void*)g,
        (__attribute__((address_space(3))) void*)l, 16, 0, 0);
}

// ---------------- fused: weights fp32->bf16 (blocks 0..255) + GN stats ------
__global__ void prep_gn(const float* __restrict__ wq, const float* __restrict__ wk,
                        const float* __restrict__ wv, const float* __restrict__ wo,
                        us* wbf, const float* __restrict__ x,
                        float* meanr, float* rstdr) {
    int tid = threadIdx.x;
    if (blockIdx.x < 256) {
        int i = blockIdx.x * 256 + tid;          // 0..65535
        const float* srcs[4] = {wq, wk, wv, wo};
        wbf[i] = f2bf(srcs[i >> 14][i & 16383]);
        return;
    }
    int bg = blockIdx.x - 256;                   // b*NG + g, 0..2047
    const float4* p = (const float4*)(x + (size_t)bg * (4 * SEQ));
    float s1 = 0.f, s2 = 0.f;
    #pragma unroll
    for (int i = 0; i < 4; i++) {
        float4 v = p[i * 256 + tid];
        s1 += v.x + v.y + v.z + v.w;
        s2 += v.x * v.x + v.y * v.y + v.z * v.z + v.w * v.w;
    }
    #pragma unroll
    for (int off = 32; off; off >>= 1) {
        s1 += __shfl_down(s1, off);
        s2 += __shfl_down(s2, off);
    }
    __shared__ float a1[4], a2[4];
    int w = tid >> 6, l = tid & 63;
    if (l == 0) { a1[w] = s1; a2[w] = s2; }
    __syncthreads();
    if (tid == 0) {
        float t1 = a1[0] + a1[1] + a1[2] + a1[3];
        float t2 = a2[0] + a2[1] + a2[2] + a2[3];
        float mean = t1 * (1.0f / (4 * SEQ));
        float var  = t2 * (1.0f / (4 * SEQ)) - mean * mean;
        meanr[bg] = mean;
        rstdr[bg] = rsqrtf(var + EPSV);
    }
}

// ---------------- fused GroupNorm-apply + QKV projection (R12, kept) --------
__global__ __launch_bounds__(256, 4) void qkv_kernel(
    const float* __restrict__ x, const float* __restrict__ gn_w,
    const float* __restrict__ gn_b, const float* __restrict__ meanr,
    const float* __restrict__ rstdr, const us* __restrict__ wbf,
    const float* __restrict__ bq, const float* __restrict__ bk,
    const float* __restrict__ bv,
    us* Q, us* K, us* Vt)
{
    __shared__ us tls[9216];                     // x-tile (pitch 136) / repack
    __shared__ float sa[CCH], sb[CCH];
    int b  = blockIdx.x >> 4;
    int s0 = (blockIdx.x & 15) * 64;
    int tid = threadIdx.x;
    const float* xb = x + (size_t)b * CCH * SEQ;

    if (tid < CCH) {
        int g = tid >> 2;
        float rs = rstdr[b * NG + g];
        float mu = meanr[b * NG + g];
        float a_ = rs * gn_w[tid];
        sa[tid] = a_;
        sb[tid] = gn_b[tid] - mu * a_;
    }
    __syncthreads();

    #pragma unroll
    for (int rep = 0; rep < 8; rep++) {
        int idx = rep * 256 + tid;               // 0..2047
        int c = idx >> 4, s4 = idx & 15;         // 4 seq elems per thread
        float4 v = *(const float4*)&xb[c * SEQ + s0 + s4 * 4];
        float a_ = sa[c], b_ = sb[c];
        int sbase = s4 * 4;
        tls[(sbase + 0) * 136 + c] = f2bf(v.x * a_ + b_);
        tls[(sbase + 1) * 136 + c] = f2bf(v.y * a_ + b_);
        tls[(sbase + 2) * 136 + c] = f2bf(v.z * a_ + b_);
        tls[(sbase + 3) * 136 + c] = f2bf(v.w * a_ + b_);
    }
    __syncthreads();

    int w = tid >> 6, lane = tid & 63;
    int m = lane & 15, quad = lane >> 4;

    // preload all x-tile A-frags (4 st x 4 ch = 64 VGPR); tls dead after
    v8s a[4][4];
    #pragma unroll
    for (int st = 0; st < 4; st++)
        #pragma unroll
        for (int ch = 0; ch < 4; ch++)
            a[st][ch] = *(const v8s*)&tls[(st * 16 + m) * 136 + ch * 32 + quad * 8];
    __syncthreads();                             // all waves preloaded

    us* Qb = Q + (size_t)b * SEQ * CCH;
    us* Kb = K + (size_t)b * SEQ * CCH;
    us* Vb = Vt + (size_t)b * CCH * SEQ;

    #pragma unroll
    for (int o = 0; o < 3; o++) {
        const us* wmat = wbf + o * 16384;
        const float* bb = (o == 0) ? bq : (o == 1) ? bk : bv;
        #pragma unroll
        for (int t2 = 0; t2 < 2; t2++) {
            int T = (o * 2 + t2) * 4 + w;        // wave-major over col-tiles
            int ct = T & 7;
            int col = ct * 16 + m;
            v8s bfr[4];
            #pragma unroll
            for (int ch = 0; ch < 4; ch++)
                bfr[ch] = *(const v8s*)&wmat[(ct * 16 + m) * 128 + ch * 32 + quad * 8];
            float bias = bb[col];
            #pragma unroll
            for (int st = 0; st < 4; st++) {
                v4f acc = {0,0,0,0};
                #pragma unroll
                for (int ch = 0; ch < 4; ch++)
                    acc = MFMA16(a[st][ch], bfr[ch], acc);
                if (o < 2) {
                    #pragma unroll
                    for (int r = 0; r < 4; r++) {
                        float v = acc[r] + bias;
                        if (o == 0) v *= QPRE;
                        tls[(st * 16 + quad * 4 + r) * 136 + col] = f2bf(v);
                    }
                } else {
                    #pragma unroll
                    for (int r = 0; r < 4; r++)
                        tls[col * 72 + st * 16 + quad * 4 + r] = f2bf(acc[r] + bias);
                }
            }
        }
        __syncthreads();                         // repack tile complete
        if (o < 2) {
            us* dst = (o == 0) ? Qb : Kb;
            #pragma unroll
            for (int rep = 0; rep < 4; rep++) {
                int idx = rep * 256 + tid;       // 0..1023
                int row = idx >> 4, c8 = idx & 15;
                *(v8s*)&dst[(size_t)(s0 + row) * 128 + c8 * 8] =
                    *(const v8s*)&tls[row * 136 + c8 * 8];
            }
        } else {
            #pragma unroll
            for (int rep = 0; rep < 4; rep++) {
                int idx = rep * 256 + tid;       // 0..1023
                int c = idx >> 3, c8 = idx & 7;
                *(v8s*)&Vb[(size_t)c * SEQ + s0 + c8 * 8] =
                    *(const v8s*)&tls[c * 72 + c8 * 8];
            }
        }
        if (o < 2) __syncthreads();              // before next matrix reuses tls
    }
}

// ---- flash attention + fused out-projection ---------------------------------
// R17: cross-tile pipeline (T15). Iteration kt computes QK(kt) AND PV(kt-1):
// PV's MFMAs are independent of QK's results, so exp/shfl(kt) overlap PV on
// separate pipes instead of serializing the QK->exp->shfl->PV chain. Carried
// state: cpa0/cpa1 (16 VGPR). K double-buffered (2x16K), V TRIPLE-buffered
// (3x16K; stage(kt+1) vs PV(kt-1) distance 2 mod 3 — never collide).
// LDS 80KB/block -> 2 blocks/CU (160KiB). Barrier/vmcnt structure = R15.
__global__ __launch_bounds__(256, 2) void attn_kernel(
    const us* __restrict__ Q, const us* __restrict__ K,
    const us* __restrict__ Vt, const us* __restrict__ wbo,
    const float* __restrict__ bo, const float* __restrict__ x,
    float* __restrict__ out)
{
    __shared__ char smem_raw[81920];             // K dbuf 32K | V tbuf 48K

    int i = blockIdx.x;
    int b  = (i & 7) * 8 + ((i >> 3) & 7);       // 8 batches per XCD
    int qt = i >> 6;                             // 0..7 (128-row q-tiles)
    int tid = threadIdx.x;
    int w = tid >> 6, lane = tid & 63;           // w in 0..3
    int m = lane & 15, quad = lane >> 4;
    int qrow0 = qt * 128 + w * 32;
    const us* Qb = Q + (size_t)b * SEQ * CCH;
    const us* Kb = K + (size_t)b * SEQ * CCH;
    const us* Vb = Vt + (size_t)b * CCH * SEQ;

    // Q as B-frags of Q^T (two 16-row stripes per wave)
    v8s aq[2][4];
    #pragma unroll
    for (int st = 0; st < 2; st++)
        #pragma unroll
        for (int ch = 0; ch < 4; ch++)
            aq[st][ch] = *(const v8s*)&Qb[(size_t)(qrow0 + st * 16 + m) * 128 + ch * 32 + quad * 8];

    v4f oacc[2][8];
    #pragma unroll
    for (int st = 0; st < 2; st++)
        #pragma unroll
        for (int ct = 0; ct < 8; ct++) oacc[st][ct] = (v4f){0, 0, 0, 0};
    float lrun[2] = {0.f, 0.f};                  // per-lane partial rowsum, q = m

    // staging: wave w stages insts j = w*4 + j4 for both K and V
    const us* kg[4]; const us* vg[4];
    int jb = w * 4;
    #pragma unroll
    for (int j4 = 0; j4 < 4; j4++) {
        int j = jb + j4;
        int kr = 4 * j + (lane >> 4);
        kg[j4] = Kb + (size_t)kr * 128 + ((lane & 15) ^ (kr & 15)) * 8;
        int vc = 8 * j + (lane >> 3);
        vg[j4] = Vb + (size_t)vc * SEQ + ((lane & 7) ^ (vc & 7)) * 8;
    }
    int idx0 = 2 * (quad & 1) * 16 + m;          // bpermute source lanes
    int idx1 = idx0 + 16;

    // prologue: stage K(0)->kbuf0, V(0)->vbuf0
    #pragma unroll
    for (int j4 = 0; j4 < 4; j4++) {
        gld_lds16(kg[j4], (us*)smem_raw + (jb + j4) * 512);
        gld_lds16(vg[j4], (us*)(smem_raw + 32768) + (jb + j4) * 512);
    }

    v8s cpa0[2], cpa1[2];                        // carried P A-frags (tile kt-1)

    for (int kt = 0; kt <= 16; kt++) {
        if (kt < 16) {
            __builtin_amdgcn_s_barrier();        // QK(kt-1)/PV(kt-2) done on bufs
            if (kt < 15) {
                int kb_n = ((kt + 1) & 1) * 16384;
                int vb_n = 32768 + ((kt + 1) % 3) * 16384;
                #pragma unroll
                for (int j4 = 0; j4 < 4; j4++) {
                    gld_lds16(kg[j4] + (size_t)(kt + 1) * 8192,
                              (us*)(smem_raw + kb_n) + (jb + j4) * 512);
                    gld_lds16(vg[j4] + (size_t)(kt + 1) * 64,
                              (us*)(smem_raw + vb_n) + (jb + j4) * 512);
                }
                asm volatile("s_waitcnt vmcnt(8)" ::: "memory");  // tile kt landed
            } else {
                asm volatile("s_waitcnt vmcnt(0)" ::: "memory");
            }
            __builtin_amdgcn_s_barrier();        // K(kt),V(kt) complete (all waves)
        }

        const us* kl = (const us*)(smem_raw + (kt & 1) * 16384);
        const us* vp = (const us*)(smem_raw + 32768 + ((kt + 2) % 3) * 16384); // (kt-1)%3

        __builtin_amdgcn_s_setprio(1);

        v4f acc0[4], acc1[4];
        int e[2][4][2];

        #define QK_STEP(c2) { \
            int krow = (c2) * 16 + m; \
            v4f A0 = {0,0,0,0}, A1 = {0,0,0,0}; \
            _Pragma("unroll") \
            for (int ch = 0; ch < 4; ch++) { \
                int chunk = (ch * 4 + quad) ^ (krow & 15); \
                v8s kb = *(const v8s*)&kl[krow * 128 + chunk * 8]; \
                A0 = MFMA16(kb, aq[0][ch], A0); \
                A1 = MFMA16(kb, aq[1][ch], A1); \
            } \
            acc0[c2] = A0; acc1[c2] = A1; }

        #define EXP_STEP(c2) { \
            float p0[4], p1[4]; \
            _Pragma("unroll") \
            for (int r = 0; r < 4; r++) { \
                p0[r] = EXP2F(acc0[c2][r]); \
                p1[r] = EXP2F(acc1[c2][r]); \
                lrun[0] += p0[r]; lrun[1] += p1[r]; \
            } \
            e[0][c2][0] = cvtpk(p0[0], p0[1]); e[0][c2][1] = cvtpk(p0[2], p0[3]); \
            e[1][c2][0] = cvtpk(p1[0], p1[1]); e[1][c2][1] = cvtpk(p1[2], p1[3]); }

        #define PV_HALF(kc2, paw) { \
            _Pragma("unroll") \
            for (int ct = 0; ct < 8; ct++) { \
                int vrow = ct * 16 + m; \
                int chunk = ((kc2) * 4 + quad) ^ (vrow & 7); \
                v8s vb = *(const v8s*)&vp[vrow * 64 + chunk * 8]; \
                oacc[0][ct] = MFMA16(paw[0], vb, oacc[0][ct]); \
                oacc[1][ct] = MFMA16(paw[1], vb, oacc[1][ct]); } }

        if (kt < 16) {
            QK_STEP(0)
            QK_STEP(1)
            QK_STEP(2)
            QK_STEP(3)
        }
        if (kt > 0) PV_HALF(0, cpa0)             // PV(kt-1), indep of QK(kt)
        if (kt < 16) {
            EXP_STEP(0)
            EXP_STEP(1)
        }
        if (kt > 0) PV_HALF(1, cpa1)
        if (kt < 16) {
            EXP_STEP(2)
            EXP_STEP(3)
            // shfl -> carried pa for next iteration (after PV consumed old)
            #pragma unroll
            for (int st = 0; st < 2; st++) {
                int c0 = (quad < 2) ? e[st][0][0] : e[st][1][0];
                int c1 = (quad < 2) ? e[st][0][1] : e[st][1][1];
                v4i t;
                t[0] = __shfl(c0, idx0);
                t[1] = __shfl(c1, idx0);
                t[2] = __shfl(c0, idx1);
                t[3] = __shfl(c1, idx1);
                cpa0[st] = __builtin_bit_cast(v8s, t);
                c0 = (quad < 2) ? e[st][2][0] : e[st][3][0];
                c1 = (quad < 2) ? e[st][2][1] : e[st][3][1];
                t[0] = __shfl(c0, idx0);
                t[1] = __shfl(c1, idx0);
                t[2] = __shfl(c0, idx1);
                t[3] = __shfl(c1, idx1);
                cpa1[st] = __builtin_bit_cast(v8s, t);
            }
        }
        __builtin_amdgcn_s_setprio(0);
        #undef QK_STEP
        #undef EXP_STEP
        #undef PV_HALF
    }

    // ---- row sums: reduce lane partials across quads (q = m per lane) ----
    float inv[2][4];
    #pragma unroll
    for (int st = 0; st < 2; st++) {
        float rs = lrun[st];
        rs += __shfl_xor(rs, 16);
        rs += __shfl_xor(rs, 32);                // rs = rowsum(q = m)
        #pragma unroll
        for (int r = 0; r < 4; r++)
            inv[st][r] = 1.0f / __shfl(rs, quad * 4 + r);
    }
    __syncthreads();                             // k/v LDS dead; reuse as olds
    us* olds = (us*)smem_raw;                    // epilogue: 128x136 = 34816 B
    #pragma unroll
    for (int st = 0; st < 2; st++)
        #pragma unroll
        for (int ct = 0; ct < 8; ct++)
            #pragma unroll
            for (int r = 0; r < 4; r++)
                olds[(w * 32 + st * 16 + quad * 4 + r) * 136 + ct * 16 + m] =
                    f2bf(oacc[st][ct][r] * inv[st][r]);
    __syncthreads();

    // ---- projection: out^T[c][s] = wo @ O^T, + bias + residual ----
    const float* xb = x + (size_t)b * CCH * SEQ;
    float* ob = out + (size_t)b * CCH * SEQ;
    int sbase = qt * 128 + w * 32;
    v8s obf[2][4];
    #pragma unroll
    for (int st = 0; st < 2; st++)
        #pragma unroll
        for (int ch = 0; ch < 4; ch++)
            obf[st][ch] = *(const v8s*)&olds[(w * 32 + st * 16 + m) * 136 + ch * 32 + quad * 8];
    #pragma unroll
    for (int mt = 0; mt < 8; mt++) {
        v8s af[4];
        #pragma unroll
        for (int ch = 0; ch < 4; ch++)
            af[ch] = *(const v8s*)&wbo[(mt * 16 + m) * 128 + ch * 32 + quad * 8];
        #pragma unroll
        for (int st = 0; st < 2; st++) {
            v4f acc = {0,0,0,0};
            #pragma unroll
            for (int ch = 0; ch < 4; ch++)
                acc = MFMA16(af[ch], obf[st][ch], acc);
            #pragma unroll
            for (int r = 0; r < 4; r++) {
                int c = mt * 16 + quad * 4 + r;
                int idx = c * SEQ + sbase + st * 16 + m;
                ob[idx] = acc[r] + bo[c] + xb[idx];
            }
        }
    }
}

extern "C" void kernel_launch(void* const* d_in, const int* in_sizes, int n_in,
                              void* d_out, int out_size, void* d_ws, size_t ws_size,
                              hipStream_t stream) {
    const float* x    = (const float*)d_in[0];
    const float* gn_w = (const float*)d_in[1];
    const float* gn_b = (const float*)d_in[2];
    const float* wq   = (const float*)d_in[3];
    const float* bq   = (const float*)d_in[4];
    const float* wk   = (const float*)d_in[5];
    const float* bk   = (const float*)d_in[6];
    const float* wv   = (const float*)d_in[7];
    const float* bv   = (const float*)d_in[8];
    const float* wo   = (const float*)d_in[9];
    const float* bo   = (const float*)d_in[10];
    float* out = (float*)d_out;

    char* ws = (char*)d_ws;
    us* wbf      = (us*)ws;
    float* meanr = (float*)(ws + 131072);
    float* rstdr = (float*)(ws + 139264);
    us* Qbuf     = (us*)(ws + 147456);
    us* Kbuf     = (us*)(ws + 147456 + 16777216ull);
    us* Vtbuf    = (us*)(ws + 147456 + 2ull * 16777216ull);

    prep_gn<<<256 + BATCH * NG, 256, 0, stream>>>(wq, wk, wv, wo, wbf, x, meanr, rstdr);
    qkv_kernel<<<1024, 256, 0, stream>>>(x, gn_w, gn_b, meanr, rstdr, wbf,
                                         bq, bk, bv, Qbuf, Kbuf, Vtbuf);
    attn_kernel<<<512, 256, 0, stream>>>(Qbuf, Kbuf, Vtbuf, wbf + 3 * 16384,
                                         bo, x, out);
}